// Round 9
// baseline (118.091 us; speedup 1.0000x reference)
//
#include <hip/hip_runtime.h>
#include <math.h>

#define FILTERS 8
#define NB 32
#define NT 16
#define NH 64
#define NW 64

typedef _Float16 f16;
typedef _Float16 half2f __attribute__((ext_vector_type(2)));
typedef _Float16 half4f __attribute__((ext_vector_type(4)));
typedef _Float16 half8f __attribute__((ext_vector_type(8)));
typedef float    floatx2 __attribute__((ext_vector_type(2)));
typedef float    floatx4 __attribute__((ext_vector_type(4)));

// LDS layout (bytes) for the 2-step fused kernel (2 output rows x 64 cols):
//  H0: 6 rows x 68 x 8ch f16 = 6528  (input h, rows r0-2..r0+3, zero halo)
//  XA: 6 rows x 68 x 4ch f16 = 3264  (x_t,   ch3==1.0 bias feed)
//  XB: 4 rows x 68 x 4ch f16 = 2176  (x_t+1, rows r0-1..r0+2)
//  H1: 4 rows x 68 x 8ch f16 = 4352  (intermediate h, rows r0-1..r0+2)
//  C1: 4 rows x 64 x 8ch f32 = 8192  (intermediate c)
#define H0OFF 0
#define XAOFF 6528
#define XBOFF 9792
#define H1OFF 11968
#define C1OFF 16320
#define SMEM_BYTES 24512

__device__ __forceinline__ float hard_sigmoid(float v) {
    return fminf(fmaxf(fmaf(0.2f, v, 0.5f), 0.0f), 1.0f);
}
__device__ __forceinline__ float fast_tanh(float v) {
    float e = __builtin_amdgcn_exp2f(v * 2.8853900817779268f);
    return 1.0f - 2.0f * __builtin_amdgcn_rcpf(e + 1.0f);
}

// ---- Weight-fragment prepack (unchanged from round 7/8, validated) ----
__global__ __launch_bounds__(256) void prepack(
    const float* __restrict__ Wx,    // (3,3,3,32)
    const float* __restrict__ Wh,    // (3,3,8,32)
    const float* __restrict__ bias,  // (32,)
    f16* __restrict__ WB)            // 4096 entries
{
    int i = blockIdx.x * 256 + threadIdx.x;
    if (i >= 4096) return;
    int e = i & 7;
    int l = (i >> 3) & 63;
    int n = (i >> 9) & 1;
    int j = i >> 10;
    int h = l >> 4;
    int g = n * 16 + (l & 15);

    float wv = 0.f;
    if (j == 0) {
        wv = Wh[(h * 8 + e) * 32 + g];
    } else if (j == 1) {
        wv = Wh[((4 + h) * 8 + e) * 32 + g];
    } else if (j == 2 && h == 0) {
        wv = Wh[(8 * 8 + e) * 32 + g];
    } else if (j == 3 && h == 3) {
        wv = (e == 3) ? bias[g] : 0.f;   // bias rides the const-1.0 patch slot
    } else {
        int ty, txp;
        if (j == 2) { ty = (h == 3) ? 1 : 0; txp = (h == 2) ? 2 : 0; }
        else        { ty = (h == 0) ? 1 : 2; txp = (h == 1) ? 0 : 2; }
        int txq = txp + (e >> 2);
        int c = e & 3;
        if (txq < 3 && c < 3)
            wv = Wx[((ty * 3 + txq) * 3 + c) * 32 + g];
    }
    WB[i] = (f16)wv;
}

#define LDA(off) ({                                                        \
    half4f lo_ = *(const half4f*)(smem + (off));                           \
    half4f hi_ = *(const half4f*)(smem + (off) + 8);                       \
    __builtin_shufflevector(lo_, hi_, 0, 1, 2, 3, 4, 5, 6, 7); })

// 8 MFMA + shuffle-exchange + gates; produces (cc0,cc1,hh0,hh1) for the
// lane's pixel and 2 filters. Validated in round 8.
#define GATE_BODY(A0, A1, A2, A3, COLD0, COLD1, CC0, CC1, HH0, HH1)        \
    {                                                                      \
        floatx4 acc0 = {0.f, 0.f, 0.f, 0.f};                               \
        floatx4 acc1 = {0.f, 0.f, 0.f, 0.f};                               \
        acc0 = __builtin_amdgcn_mfma_f32_16x16x32_f16(B00, A0, acc0,0,0,0);\
        acc1 = __builtin_amdgcn_mfma_f32_16x16x32_f16(B01, A0, acc1,0,0,0);\
        acc0 = __builtin_amdgcn_mfma_f32_16x16x32_f16(B10, A1, acc0,0,0,0);\
        acc1 = __builtin_amdgcn_mfma_f32_16x16x32_f16(B11, A1, acc1,0,0,0);\
        acc0 = __builtin_amdgcn_mfma_f32_16x16x32_f16(B20, A2, acc0,0,0,0);\
        acc1 = __builtin_amdgcn_mfma_f32_16x16x32_f16(B21, A2, acc1,0,0,0);\
        acc0 = __builtin_amdgcn_mfma_f32_16x16x32_f16(B30, A3, acc0,0,0,0);\
        acc1 = __builtin_amdgcn_mfma_f32_16x16x32_f16(B31, A3, acc1,0,0,0);\
        float ex0 = (g4 & 2) ? acc0[0] : acc0[2];                          \
        float ex1 = (g4 & 2) ? acc0[1] : acc0[3];                          \
        float ex2 = (g4 & 2) ? acc1[0] : acc1[2];                          \
        float ex3 = (g4 & 2) ? acc1[1] : acc1[3];                          \
        ex0 = __shfl_xor(ex0, 32, 64);                                     \
        ex1 = __shfl_xor(ex1, 32, 64);                                     \
        ex2 = __shfl_xor(ex2, 32, 64);                                     \
        ex3 = __shfl_xor(ex3, 32, 64);                                     \
        float zi0, zi1, zf0, zf1, zc0, zc1, zo0, zo1;                      \
        if (g4 & 2) {                                                      \
            zi0 = ex0;     zi1 = ex1;     zf0 = acc0[2]; zf1 = acc0[3];    \
            zc0 = ex2;     zc1 = ex3;     zo0 = acc1[2]; zo1 = acc1[3];    \
        } else {                                                           \
            zi0 = acc0[0]; zi1 = acc0[1]; zf0 = ex0;     zf1 = ex1;        \
            zc0 = acc1[0]; zc1 = acc1[1]; zo0 = ex2;     zo1 = ex3;        \
        }                                                                  \
        float ig0 = hard_sigmoid(zi0), fg0 = hard_sigmoid(zf0);            \
        float cg0 = fast_tanh(zc0),    og0 = hard_sigmoid(zo0);            \
        CC0 = fmaf(fg0, COLD0, ig0 * cg0);                                 \
        HH0 = og0 * fast_tanh(CC0);                                        \
        float ig1 = hard_sigmoid(zi1), fg1 = hard_sigmoid(zf1);            \
        float cg1 = fast_tanh(zc1),    og1 = hard_sigmoid(zo1);            \
        CC1 = fmaf(fg1, COLD1, ig1 * cg1);                                 \
        HH1 = og1 * fast_tanh(CC1);                                        \
    }

// Fused 2-timestep kernel. Block = 256 threads (4 waves), output 2 rows x 64
// cols of one batch at time t+1. Step A computes the intermediate h/c for a
// 4-row band into LDS (halo recompute); step B consumes it.
// Grid = 32 batches x 32 row-groups = 1024 blocks -> 4 blocks/CU.
__global__ __launch_bounds__(256, 4) void convlstm_step2(
    const float* __restrict__ x,     // (B,T,H,W,3) f32
    const f16*   __restrict__ WB,    // prepacked weight fragments
    const f16*   __restrict__ h_in,  // (B,H,W,8) f16  (h_{t-1})
    f16*         __restrict__ h_out, // (B,H,W,8) f16  (h_{t+1})
    float*       __restrict__ c_buf, // (B,H,W,8) f32  (in: c_{t-1}, out: c_{t+1})
    int t, int first)
{
    __shared__ __attribute__((aligned(16))) char smem[SMEM_BYTES];

    const int bid = blockIdx.x;
    const int bi  = bid >> 5;
    const int r0  = (bid & 31) << 1;
    const int tid = threadIdx.x;
    const int w    = __builtin_amdgcn_readfirstlane(tid >> 6);  // wave 0..3
    const int lane = tid & 63;
    const int p16  = lane & 15;
    const int g4   = lane >> 4;

    const float* xA = x + (((size_t)bi * NT + t) * 4096) * 3;
    const float* xB = xA + 4096 * 3;

    // ---- stage H0 + XA: 6 rows (r0-2..r0+3) x 68 cols ----
    for (int i = tid; i < 408; i += 256) {
        int lr = i / 68;
        int lc = i - lr * 68;
        int gr = r0 - 2 + lr;
        int gc = lc - 1;
        bool ok = ((unsigned)gr < 64u) && ((unsigned)gc < 64u);
        half4f xv = {0, 0, 0, (f16)1.0f};
        half8f hv = {0, 0, 0, 0, 0, 0, 0, 0};
        if (ok) {
            const float* xp = xA + (gr * 64 + gc) * 3;
            xv[0] = (f16)xp[0]; xv[1] = (f16)xp[1]; xv[2] = (f16)xp[2];
            if (!first)
                hv = *(const half8f*)(h_in + ((size_t)(bi * 4096 + gr * 64 + gc)) * 8);
        }
        *(half8f*)(smem + H0OFF + i * 16) = hv;
        *(half4f*)(smem + XAOFF + i * 8)  = xv;
    }
    // ---- stage XB: 4 rows (r0-1..r0+2); zero entire H1 plane ----
    for (int i = tid; i < 272; i += 256) {
        int lr = i / 68;
        int lc = i - lr * 68;
        int gr = r0 - 1 + lr;
        int gc = lc - 1;
        half4f xv = {0, 0, 0, (f16)1.0f};
        if (((unsigned)gr < 64u) && ((unsigned)gc < 64u)) {
            const float* xp = xB + (gr * 64 + gc) * 3;
            xv[0] = (f16)xp[0]; xv[1] = (f16)xp[1]; xv[2] = (f16)xp[2];
        }
        *(half4f*)(smem + XBOFF + i * 8) = xv;
        half8f zz = {0, 0, 0, 0, 0, 0, 0, 0};
        *(half8f*)(smem + H1OFF + i * 16) = zz;
    }

    // ---- weight fragments (wave-invariant) ----
    const half8f* WBv = (const half8f*)WB;
    half8f B00 = WBv[0 * 64 + lane], B01 = WBv[1 * 64 + lane];
    half8f B10 = WBv[2 * 64 + lane], B11 = WBv[3 * 64 + lane];
    half8f B20 = WBv[4 * 64 + lane], B21 = WBv[5 * 64 + lane];
    half8f B30 = WBv[6 * 64 + lane], B31 = WBv[7 * 64 + lane];

    // ---- c0 prefetch for step A (row rA = r0-1+w, 4 col-tiles) ----
    const int f0 = (g4 & 1) * 4 + (g4 & 2);
    const int rA = r0 - 1 + w;
    const bool validA = ((unsigned)rA < 64u);
    floatx2 c0v0 = {0.f, 0.f}, c0v1 = {0.f, 0.f};
    floatx2 c0v2 = {0.f, 0.f}, c0v3 = {0.f, 0.f};
    if (!first && validA) {
        const float* cb = c_buf + ((size_t)(bi * 4096 + rA * 64 + p16)) * 8 + f0;
        c0v0 = *(const floatx2*)(cb);
        c0v1 = *(const floatx2*)(cb + 16 * 8);
        c0v2 = *(const floatx2*)(cb + 32 * 8);
        c0v3 = *(const floatx2*)(cb + 48 * 8);
    }

    // tap->offset constants (shared by both steps; validated round 7/8)
    const int ty0 = (g4 >= 3) ? 1 : 0, tx0 = g4 - 3 * ty0;
    const int ty1 = 1 + ((g4 >= 2) ? 1 : 0), tx1 = (g4 + 4) - 3 * ty1;
    const int ty2 = (g4 == 3) ? 1 : 0, tx2 = (g4 == 2) ? 2 : 0;
    const int ty3 = (g4 == 0) ? 1 : 2, tx3 = (g4 == 1) ? 0 : 2;
    const int inc2 = (g4 == 0) ? 256 : 128;

    __syncthreads();

    // ======== STEP A: wave w -> band row rA, 4 col-tiles of 16 ========
    {
        int o0 = H0OFF + ((w + ty0) * 68 + p16 + tx0) * 16;
        int o1 = H0OFF + ((w + ty1) * 68 + p16 + tx1) * 16;
        int o2 = (g4 == 0) ? H0OFF + ((w + 2) * 68 + p16 + 2) * 16
                           : XAOFF + ((w + ty2) * 68 + p16 + tx2) * 8;
        int o3 = XAOFF + ((w + ty3) * 68 + p16 + tx3) * 8;

        #pragma unroll
        for (int tt = 0; tt < 4; ++tt) {
            half8f a0 = LDA(o0);
            half8f a1 = LDA(o1);
            half8f a2 = LDA(o2);
            half8f a3 = LDA(o3);
            floatx2 cold = (tt == 0) ? c0v0 : (tt == 1) ? c0v1
                         : (tt == 2) ? c0v2 : c0v3;
            float cc0, cc1, hh0, hh1;
            GATE_BODY(a0, a1, a2, a3, cold[0], cold[1], cc0, cc1, hh0, hh1);
            if (!validA) { hh0 = 0.f; hh1 = 0.f; }   // out-of-image band row
            half2f hw = {(f16)hh0, (f16)hh1};
            *(half2f*)(smem + H1OFF + (w * 68 + 1 + tt * 16 + p16) * 16 + f0 * 2) = hw;
            floatx2 cw = {cc0, cc1};
            *(floatx2*)(smem + C1OFF + ((w * 64 + tt * 16 + p16) * 8 + f0) * 4) = cw;
            o0 += 256; o1 += 256; o2 += inc2; o3 += 128;
        }
    }

    __syncthreads();

    // ======== STEP B: wave w -> row r0+(w>>1), col half (w&1)*32, 2 tiles ====
    {
        const int prB  = w >> 1;
        const int wcol = (w & 1) << 5;
        int o0 = H1OFF + ((prB + ty0) * 68 + wcol + p16 + tx0) * 16;
        int o1 = H1OFF + ((prB + ty1) * 68 + wcol + p16 + tx1) * 16;
        int o2 = (g4 == 0) ? H1OFF + ((prB + 2) * 68 + wcol + p16 + 2) * 16
                           : XBOFF + ((prB + ty2) * 68 + wcol + p16 + tx2) * 8;
        int o3 = XBOFF + ((prB + ty3) * 68 + wcol + p16 + tx3) * 8;

        const size_t rowb = (size_t)(bi * 4096 + (r0 + prB) * 64);

        #pragma unroll
        for (int tt = 0; tt < 2; ++tt) {
            const int col = wcol + tt * 16 + p16;
            half8f a0 = LDA(o0);
            half8f a1 = LDA(o1);
            half8f a2 = LDA(o2);
            half8f a3 = LDA(o3);
            floatx2 c1v = *(const floatx2*)(smem + C1OFF +
                              (((prB + 1) * 64 + col) * 8 + f0) * 4);
            float cc0, cc1, hh0, hh1;
            GATE_BODY(a0, a1, a2, a3, c1v[0], c1v[1], cc0, cc1, hh0, hh1);
            const size_t gp = rowb + col;
            floatx2 cw = {cc0, cc1};
            *(floatx2*)(c_buf + gp * 8 + f0) = cw;
            half2f hw = {(f16)hh0, (f16)hh1};
            *(half2f*)(h_out + gp * 8 + f0) = hw;
            o0 += 256; o1 += 256; o2 += inc2; o3 += 128;
        }
    }
}

// Stage 1: 512 blocks (32 batches x 16 chunks); each reduces 2048 elements.
__global__ __launch_bounds__(256) void head_partial(
    const f16* __restrict__ h,       // (B, 32768) f16
    const float* __restrict__ Wout,  // (32768, 4)
    float* __restrict__ partial)     // (B*16, 4)
{
    const int b = blockIdx.x >> 4;
    const int chunk = blockIdx.x & 15;
    const int tid = threadIdx.x;
    const f16* hb = h + (size_t)b * 32768 + chunk * 2048;
    const float* wb = Wout + (size_t)(chunk * 2048) * 4;

    float acc[4] = {0.f, 0.f, 0.f, 0.f};
    #pragma unroll
    for (int it = 0; it < 8; ++it) {
        int i = it * 256 + tid;
        float hv = (float)hb[i];
        float4 wv = *(const float4*)(wb + (size_t)i * 4);
        acc[0] = fmaf(hv, wv.x, acc[0]);
        acc[1] = fmaf(hv, wv.y, acc[1]);
        acc[2] = fmaf(hv, wv.z, acc[2]);
        acc[3] = fmaf(hv, wv.w, acc[3]);
    }
    #pragma unroll
    for (int j = 0; j < 4; ++j)
        #pragma unroll
        for (int off = 32; off >= 1; off >>= 1)
            acc[j] += __shfl_down(acc[j], off, 64);

    __shared__ float red[4][4];
    int lane = tid & 63, wv2 = tid >> 6;
    if (lane == 0) {
        #pragma unroll
        for (int j = 0; j < 4; ++j) red[wv2][j] = acc[j];
    }
    __syncthreads();
    if (tid == 0) {
        #pragma unroll
        for (int j = 0; j < 4; ++j)
            partial[(size_t)blockIdx.x * 4 + j] =
                red[0][j] + red[1][j] + red[2][j] + red[3][j];
    }
}

__global__ __launch_bounds__(64) void head_finish(
    const float* __restrict__ partial,  // (B*16, 4)
    const float* __restrict__ bout,     // (4,)
    float* __restrict__ out)            // (B, 4)
{
    int b = threadIdx.x;
    if (b >= NB) return;
    float logit[4] = {bout[0], bout[1], bout[2], bout[3]};
    #pragma unroll
    for (int k = 0; k < 16; ++k) {
        const float* p = partial + (size_t)(b * 16 + k) * 4;
        logit[0] += p[0]; logit[1] += p[1]; logit[2] += p[2]; logit[3] += p[3];
    }
    float m = fmaxf(fmaxf(logit[0], logit[1]), fmaxf(logit[2], logit[3]));
    float e[4], s = 0.f;
    #pragma unroll
    for (int j = 0; j < 4; ++j) { e[j] = expf(logit[j] - m); s += e[j]; }
    float inv = 1.0f / s;
    #pragma unroll
    for (int j = 0; j < 4; ++j) out[b * 4 + j] = e[j] * inv;
}

extern "C" void kernel_launch(void* const* d_in, const int* in_sizes, int n_in,
                              void* d_out, int out_size, void* d_ws, size_t ws_size,
                              hipStream_t stream) {
    const float* x    = (const float*)d_in[0];
    const float* Wx   = (const float*)d_in[1];
    const float* Wh   = (const float*)d_in[2];
    const float* b    = (const float*)d_in[3];
    const float* Wout = (const float*)d_in[4];
    const float* bout = (const float*)d_in[5];
    float* out = (float*)d_out;

    char* ws = (char*)d_ws;
    f16*   hA      = (f16*)ws;                       // 2 MB
    f16*   hB      = (f16*)(ws + (1u << 21));        // 2 MB
    float* cb      = (float*)(ws + (1u << 22));      // 4 MB
    f16*   WB      = (f16*)(ws + (1u << 23));        // 8 KB
    float* partial = (float*)(ws + (1u << 23) + 8192);

    prepack<<<16, 256, 0, stream>>>(Wx, Wh, b, WB);

    // 8 fused kernels, 2 timesteps each. k=0: in hA (unused), out hB;
    // alternate; k=7: out hA -> head reads hA.
    for (int k = 0; k < 8; ++k) {
        const f16* hin = (k & 1) ? hB : hA;
        f16*       hout = (k & 1) ? hA : hB;
        convlstm_step2<<<1024, 256, 0, stream>>>(x, WB, hin, hout, cb,
                                                 2 * k, (k == 0) ? 1 : 0);
    }
    head_partial<<<512, 256, 0, stream>>>(hA, Wout, partial);
    head_finish<<<1, 64, 0, stream>>>(partial, bout, out);
}